// Round 2
// 71.402 us; speedup vs baseline: 1.0486x; 1.0486x over previous
//
#include <hip/hip_runtime.h>
#include <math.h>

// out[p] = prod_l (1 - V[l,p]) * poly(wl[p])
//   V = A_l/(gamma^2+d^2) + A_g*exp(n2*d^2),  d = wl - lam
//
// Fully fused single kernel, 4-wave line-split version:
//  - per 64-px block, binary-search the sorted line list for the +/-10 A band.
//    Lorentzian tail-sum beyond D: ~0.0072/D -> 7e-4 at D=10, 30x under the
//    2e-2 threshold (unchanged from verified baseline).
//  - block = 256 threads = 4 waves over the SAME 64 pixels; wave w takes
//    lines i ≡ w (mod 4) of the band and partial products are combined via
//    LDS. Old layout was 1563 single-wave blocks = 1.53 waves/SIMD -- pure
//    latency exposure (12-deep search chain, LDS+transcendental latency,
//    half-empty second scheduling round). New layout: 6252 waves = 24.4
//    waves/CU, whole grid resident in ONE round; per-wave critical path /4.
//  - search deduplicated to wave 0; both bounds searched simultaneously
//    (even lanes search lo-bound, odd lanes hi-bound) -> one 12-round chain
//    per block instead of two per wave.
//  - Gaussian gated on |d| < 3.5 A (8*sigma_max: exp(-32) ~ 1e-14); 64-px
//    span is 1.3 A so the gate is nearly wave-uniform.
//  - 2 independent product accumulators per wave (8-ish lines/wave).

#define PX       64
#define NW       4
#define NTHREADS (PX * NW)
#define D_LOR    10.0f
#define D_GAU    3.5f
#define TILE     64

__device__ __forceinline__ int lower_bound_f(const float* __restrict__ a,
                                             int n, float v) {
    int lo = 0, len = n;
    while (len > 0) {
        int half = len >> 1;
        int mid = lo + half;
        if (a[mid] < v) { lo = mid + 1; len -= half + 1; }
        else            { len = half; }
    }
    return lo;
}

__global__ void __launch_bounds__(NTHREADS) fused_voigt_kernel(
        const float* __restrict__ wl,
        const float* __restrict__ lam,
        const float* __restrict__ amp_log,
        const float* __restrict__ sig_log,
        const float* __restrict__ gam_log,
        const float* __restrict__ a_c,
        const float* __restrict__ b_c,
        const float* __restrict__ c_c,
        float* __restrict__ out,
        int n_pix, int n_lines) {
    __shared__ float4 q_s[TILE];      // lam, Al, gamma^2, n2
    __shared__ float  ag_s[TILE];     // Ag
    __shared__ float  part[NW][PX];   // per-wave partial products
    __shared__ int    bnd[2];         // lo, hi

    const int tid  = threadIdx.x;
    const int wv   = tid >> 6;
    const int lane = tid & 63;
    const int p    = blockIdx.x * PX + lane;
    const int pc   = min(p, n_pix - 1);
    const float w  = wl[pc];

    // hoist poly coeffs early so the s_loads overlap everything else
    const float ac = a_c[0];
    const float bc = b_c[0];
    const float cc = c_c[0];

    if (wv == 0) {
        // lane-parallel: even lanes search the lower bound, odd lanes the
        // upper bound -> one dependent-load chain instead of two.
        const float w0 = __shfl(w, 0)      - D_LOR;
        const float w1 = __shfl(w, PX - 1) + D_LOR;
        const float v  = (lane & 1) ? w1 : w0;
        const int r = lower_bound_f(lam, n_lines, v);
        if (lane < 2) bnd[lane] = r;
    }
    __syncthreads();
    const int lo = bnd[0];
    const int hi = bnd[1];

    float prod0 = 1.0f, prod1 = 1.0f;

    for (int t = lo; t < hi; t += TILE) {
        const int nt = min(TILE, hi - t);
        __syncthreads();          // all waves done reading previous tile
        if (tid < nt) {
            const int l = t + tid;
            float sigma = __expf(sig_log[l]);
            float gamma = __expf(gam_log[l]);
            float amp   = __expf(amp_log[l]);
            float fG = 2.3548f * sigma;
            float fL = 2.0f * gamma;
            float fG2 = fG * fG, fL2 = fL * fL;
            float fwhm5 = fG2 * fG2 * fG
                        + 2.69269f * fG2 * fG2 * fL
                        + 2.42843f * fG2 * fG  * fL2
                        + 4.47163f * fG2 * fL2 * fL
                        + 0.07842f * fG  * fL2 * fL2
                        + fL2 * fL2 * fL;
            float fwhm = __expf(0.2f * __logf(fwhm5));   // fwhm5^(1/5)
            float fr   = fL * __builtin_amdgcn_rcpf(fwhm);
            float eta  = fr * (1.36603f + fr * (-0.47719f + fr * 0.11116f));
            float Al   = amp * eta * gamma * (1.0f / 3.141592654f);
            float Ag   = amp * (1.0f - eta) *
                         __builtin_amdgcn_rcpf(sigma * 2.5066f);
            q_s[tid]  = make_float4(lam[l], Al, gamma * gamma,
                                    -0.5f / (sigma * sigma));
            ag_s[tid] = Ag;
        }
        __syncthreads();

        // wave wv processes lines i = wv, wv+NW, ... ; 2-deep ILP
        int i = wv;
        for (; i + NW < nt; i += 2 * NW) {
            float4 qa = q_s[i];
            float4 qb = q_s[i + NW];
            float da = w - qa.x, db = w - qb.x;
            float da2 = da * da, db2 = db * db;
            float va = qa.y * __builtin_amdgcn_rcpf(qa.z + da2);
            float vb = qb.y * __builtin_amdgcn_rcpf(qb.z + db2);
            if (fabsf(da) < D_GAU) va += ag_s[i]      * __expf(qa.w * da2);
            if (fabsf(db) < D_GAU) vb += ag_s[i + NW] * __expf(qb.w * db2);
            prod0 *= (1.0f - va);
            prod1 *= (1.0f - vb);
        }
        for (; i < nt; i += NW) {
            float4 q = q_s[i];
            float d  = w - q.x;
            float d2 = d * d;
            float v  = q.y * __builtin_amdgcn_rcpf(q.z + d2);
            if (fabsf(d) < D_GAU) v += ag_s[i] * __expf(q.w * d2);
            prod0 *= (1.0f - v);
        }
    }

    part[wv][lane] = prod0 * prod1;
    __syncthreads();

    if (wv == 0 && p < n_pix) {
        float wn = (w - 10500.0f) * (1.0f / 2500.0f);
        float poly = ac + wn * (bc + wn * cc);
        out[p] = (part[0][lane] * part[1][lane]) *
                 (part[2][lane] * part[3][lane]) * poly;
    }
}

extern "C" void kernel_launch(void* const* d_in, const int* in_sizes, int n_in,
                              void* d_out, int out_size, void* d_ws, size_t ws_size,
                              hipStream_t stream) {
    const float* wl      = (const float*)d_in[0];
    const float* lam     = (const float*)d_in[1];
    const float* amp_log = (const float*)d_in[2];
    const float* sig_log = (const float*)d_in[3];
    const float* gam_log = (const float*)d_in[4];
    const float* a_c     = (const float*)d_in[5];
    const float* b_c     = (const float*)d_in[6];
    const float* c_c     = (const float*)d_in[7];
    float* out = (float*)d_out;

    int n_pix   = in_sizes[0];
    int n_lines = in_sizes[1];
    int n_blocks = (n_pix + PX - 1) / PX;

    fused_voigt_kernel<<<n_blocks, NTHREADS, 0, stream>>>(
        wl, lam, amp_log, sig_log, gam_log, a_c, b_c, c_c, out,
        n_pix, n_lines);
}

// Round 3
// 69.402 us; speedup vs baseline: 1.0788x; 1.0288x over previous
//
#include <hip/hip_runtime.h>
#include <math.h>

// out[p] = prod_l (1 - V[l,p]) * poly(wl[p])
//   V = A_l/(gamma^2+d^2) + A_g*exp(n2*d^2),  d = wl - lam
//
// Fully fused single kernel, 4-wave line-split version:
//  - per 64-px block, find the +/-10 A line band with a SAMPLED 2-round
//    wave-parallel lower_bound (64 lanes probe evenly spaced entries,
//    ballot+popc brackets a <=ceil(n/64)-entry range, round 2 resolves it).
//    Replaces the 12-deep dependent-load binary search chain (~2.4k cy of
//    pure L2 latency) with 2 dependent rounds (~0.5k cy). Waves 0/1 search
//    lo/hi concurrently.
//  - Lorentzian tail-sum beyond D: ~0.0072/D -> 7e-4 at D=10, 30x under the
//    2e-2 threshold (unchanged from verified baseline).
//  - block = 256 threads = 4 waves over the SAME 64 pixels; wave w takes
//    lines i ≡ w (mod 4) of the band; partial products combined via LDS.
//    6252 waves = 24.4 waves/CU -> whole grid resident in ONE round; kernel
//    time ~= per-block critical path, hence the focus on the search chain.
//  - Gaussian gated on |d| < 3.5 A (8*sigma_max: exp(-32) ~ 1e-14); 64-px
//    span is 1.3 A so the gate is nearly wave-uniform.
//  - barrier structure: stage -> barrier -> compute -> (barrier only if
//    another tile). Single-tile common case (~32-line band) pays 3 barriers
//    total instead of 4.

#define PX       64
#define NW       4
#define NTHREADS (PX * NW)
#define D_LOR    10.0f
#define D_GAU    3.5f
#define TILE     64

// lower_bound over sorted a[0..n) executed by one full wave; 2 dependent
// load rounds. All 64 lanes must participate (ballot).
__device__ __forceinline__ int wave_lower_bound(const float* __restrict__ a,
                                                int n, float v, int lane) {
    const int step = (n + 63) >> 6;              // ceil(n/64)
    // round 1: probe a[lane*step]
    int idx = lane * step;
    bool valid = idx < n;
    float x = a[valid ? idx : (n - 1)];
    unsigned long long m = __ballot(valid && (x < v));
    int j = __popcll(m);                          // # probes < v
    // bound is in ((j-1)*step, j*step]; j==0 -> bound 0
    int b = (j == 0) ? 0 : (j - 1) * step + 1;
    // round 2: probe a[b+lane] for lane < step
    int idx2 = b + lane;
    bool valid2 = (lane < step) && (idx2 < n);
    float x2 = a[valid2 ? idx2 : (n - 1)];
    unsigned long long m2 = __ballot(valid2 && (x2 < v));
    return b + __popcll(m2);
}

__global__ void __launch_bounds__(NTHREADS) fused_voigt_kernel(
        const float* __restrict__ wl,
        const float* __restrict__ lam,
        const float* __restrict__ amp_log,
        const float* __restrict__ sig_log,
        const float* __restrict__ gam_log,
        const float* __restrict__ a_c,
        const float* __restrict__ b_c,
        const float* __restrict__ c_c,
        float* __restrict__ out,
        int n_pix, int n_lines) {
    __shared__ float4 q_s[TILE];      // lam, Al, gamma^2, n2
    __shared__ float  ag_s[TILE];     // Ag
    __shared__ float  part[NW][PX];   // per-wave partial products
    __shared__ int    bnd[2];         // lo, hi

    const int tid  = threadIdx.x;
    const int wv   = tid >> 6;
    const int lane = tid & 63;
    const int p    = blockIdx.x * PX + lane;
    const int pc   = min(p, n_pix - 1);
    const float w  = wl[pc];

    // hoist poly coeffs early so the s_loads overlap everything else
    const float ac = a_c[0];
    const float bc = b_c[0];
    const float cc = c_c[0];

    if (wv < 2) {
        // waves 0/1 hold identical w vectors (same 64 pixels); wave 0
        // resolves the lower bound, wave 1 the upper bound, concurrently.
        const float wb = __shfl(w, (wv == 0) ? 0 : PX - 1);
        const float v  = (wv == 0) ? (wb - D_LOR) : (wb + D_LOR);
        const int r = wave_lower_bound(lam, n_lines, v, lane);
        if (lane == 0) bnd[wv] = r;
    }
    __syncthreads();
    const int lo = bnd[0];
    const int hi = bnd[1];

    float prod0 = 1.0f, prod1 = 1.0f;

    for (int t = lo; t < hi; t += TILE) {
        const int nt = min(TILE, hi - t);
        if (tid < nt) {
            const int l = t + tid;
            float sigma = __expf(sig_log[l]);
            float gamma = __expf(gam_log[l]);
            float amp   = __expf(amp_log[l]);
            float fG = 2.3548f * sigma;
            float fL = 2.0f * gamma;
            float fG2 = fG * fG, fL2 = fL * fL;
            float fwhm5 = fG2 * fG2 * fG
                        + 2.69269f * fG2 * fG2 * fL
                        + 2.42843f * fG2 * fG  * fL2
                        + 4.47163f * fG2 * fL2 * fL
                        + 0.07842f * fG  * fL2 * fL2
                        + fL2 * fL2 * fL;
            float fwhm = __expf(0.2f * __logf(fwhm5));   // fwhm5^(1/5)
            float fr   = fL * __builtin_amdgcn_rcpf(fwhm);
            float eta  = fr * (1.36603f + fr * (-0.47719f + fr * 0.11116f));
            float Al   = amp * eta * gamma * (1.0f / 3.141592654f);
            float Ag   = amp * (1.0f - eta) *
                         __builtin_amdgcn_rcpf(sigma * 2.5066f);
            q_s[tid]  = make_float4(lam[l], Al, gamma * gamma,
                                    -0.5f / (sigma * sigma));
            ag_s[tid] = Ag;
        }
        __syncthreads();          // staging visible to all waves

        // wave wv processes lines i = wv, wv+NW, ... ; 2-deep ILP
        int i = wv;
        for (; i + NW < nt; i += 2 * NW) {
            float4 qa = q_s[i];
            float4 qb = q_s[i + NW];
            float da = w - qa.x, db = w - qb.x;
            float da2 = da * da, db2 = db * db;
            float va = qa.y * __builtin_amdgcn_rcpf(qa.z + da2);
            float vb = qb.y * __builtin_amdgcn_rcpf(qb.z + db2);
            if (fabsf(da) < D_GAU) va += ag_s[i]      * __expf(qa.w * da2);
            if (fabsf(db) < D_GAU) vb += ag_s[i + NW] * __expf(qb.w * db2);
            prod0 *= (1.0f - va);
            prod1 *= (1.0f - vb);
        }
        for (; i < nt; i += NW) {
            float4 q = q_s[i];
            float d  = w - q.x;
            float d2 = d * d;
            float v  = q.y * __builtin_amdgcn_rcpf(q.z + d2);
            if (fabsf(d) < D_GAU) v += ag_s[i] * __expf(q.w * d2);
            prod0 *= (1.0f - v);
        }

        if (t + TILE < hi) __syncthreads();   // uniform; protect re-staging
    }

    part[wv][lane] = prod0 * prod1;
    __syncthreads();

    if (wv == 0 && p < n_pix) {
        float wn = (w - 10500.0f) * (1.0f / 2500.0f);
        float poly = ac + wn * (bc + wn * cc);
        out[p] = (part[0][lane] * part[1][lane]) *
                 (part[2][lane] * part[3][lane]) * poly;
    }
}

extern "C" void kernel_launch(void* const* d_in, const int* in_sizes, int n_in,
                              void* d_out, int out_size, void* d_ws, size_t ws_size,
                              hipStream_t stream) {
    const float* wl      = (const float*)d_in[0];
    const float* lam     = (const float*)d_in[1];
    const float* amp_log = (const float*)d_in[2];
    const float* sig_log = (const float*)d_in[3];
    const float* gam_log = (const float*)d_in[4];
    const float* a_c     = (const float*)d_in[5];
    const float* b_c     = (const float*)d_in[6];
    const float* c_c     = (const float*)d_in[7];
    float* out = (float*)d_out;

    int n_pix   = in_sizes[0];
    int n_lines = in_sizes[1];
    int n_blocks = (n_pix + PX - 1) / PX;

    fused_voigt_kernel<<<n_blocks, NTHREADS, 0, stream>>>(
        wl, lam, amp_log, sig_log, gam_log, a_c, b_c, c_c, out,
        n_pix, n_lines);
}